// Round 1
// baseline (40739.960 us; speedup 1.0000x reference)
//
#include <hip/hip_runtime.h>
#include <stdint.h>

// ---------------------------------------------------------------------------
// complexLSTM: T=512, B=64, H=512, L=2
// Persistent-kernel design:
//   - packed weights: for each layer, A_cat[k=2048][n=4096] bf16 where
//     u = [xr | xi | hr | hi] (K=2048) and cols n = (d*8 + g), g in
//     {ir,fr,gr,or, ii,fi,gi,oi}, so g[b,n] = sum_k u[b,k] A_cat[k,n] + bias[n]
//   - 256 blocks (1 per CU, forced by ~140KB LDS), block = (layer, 32-col chunk)
//   - layer pipelining: layer l active during phases p in [l, l+512), t = p-l
//   - h exchanged via global 2-slot bf16 ring per layer; c in registers
//   - hand-rolled grid barrier (all 256 blocks co-resident by construction)
// ---------------------------------------------------------------------------

#define KPAD 2056      // LDS row stride in bf16 elems (2048 + 8 pad)
#define NPHASE 513

typedef __attribute__((ext_vector_type(8))) short short8;
typedef __attribute__((ext_vector_type(4))) float floatx4;

#define OFF_W    256u
#define SZ_W     (2u*4096u*2048u*2u)        // 33,554,432  packed bf16 weights
#define OFF_BIAS (OFF_W + SZ_W)             // 33,554,688  packed fp32 bias
#define SZ_BIAS  (2u*4096u*4u)
#define OFF_H    (OFF_BIAS + SZ_BIAS)       // 33,587,456  h rings [L][2][64][1024] bf16
#define SZ_H     (2u*2u*64u*1024u*2u)
#define OFF_XBF  (OFF_H + SZ_H)             // 34,111,744  optional bf16 x cache
#define SZ_XBF   (512u*64u*1024u*2u)        // 67,108,864
#define NEED_XBF ((size_t)OFF_XBF + SZ_XBF) // ~96.6 MB
#define NEED_BASE ((size_t)OFF_XBF)         // ~32.5 MB

__device__ __forceinline__ unsigned short f2bf(float f) {
  union { float f; uint32_t u; } v; v.f = f;
  uint32_t u = v.u;
  uint32_t r = (u + 0x7fffu + ((u >> 16) & 1u)) >> 16;   // RNE
  return (unsigned short)r;
}
__device__ __forceinline__ float sigm(float x)  { return 1.0f / (1.0f + __expf(-x)); }
__device__ __forceinline__ float tanhf_(float x){ return 1.0f - 2.0f / (1.0f + __expf(2.0f * x)); }

// ---------------- prep kernels ----------------

__global__ void pack_weights_k(const float* __restrict__ Wi_r, const float* __restrict__ Wi_i,
                               const float* __restrict__ Wh_r, const float* __restrict__ Wh_i,
                               unsigned short* __restrict__ wp) {
  uint32_t idx = blockIdx.x * 256u + threadIdx.x;   // < 16,777,216
  int k  = idx & 2047;
  int cp = (idx >> 11) & 4095;
  int l  = idx >> 23;
  int nb = cp >> 5, cl = cp & 31;
  int dd = cl >> 3, g = cl & 7;
  int d  = nb * 4 + dd;
  int j  = (g & 3) * 512 + d;          // row in the (4H,H) weight
  int seg = k >> 9, kk = k & 511;
  bool im = (g >= 4);
  const float* src; float sgn = 1.0f;
  if (seg == 0)      { src = im ? Wi_i : Wi_r; }                         // * xr
  else if (seg == 1) { src = im ? Wi_r : Wi_i; if (!im) sgn = -1.0f; }   // * xi
  else if (seg == 2) { src = im ? Wh_i : Wh_r; }                         // * hr
  else               { src = im ? Wh_r : Wh_i; if (!im) sgn = -1.0f; }   // * hi
  float v = sgn * src[((size_t)l * 2048 + j) * 512 + kk];
  wp[idx] = f2bf(v);
}

__global__ void pack_bias_k(const float* __restrict__ bi_r, const float* __restrict__ bi_i,
                            const float* __restrict__ bh_r, const float* __restrict__ bh_i,
                            float* __restrict__ bp) {
  uint32_t idx = blockIdx.x * 256u + threadIdx.x;   // < 8192
  int cp = idx & 4095, l = idx >> 12;
  int nb = cp >> 5, cl = cp & 31, dd = cl >> 3, g = cl & 7;
  int j = (g & 3) * 512 + nb * 4 + dd;
  float v = (g >= 4) ? (bi_i[l * 2048 + j] + bh_i[l * 2048 + j])
                     : (bi_r[l * 2048 + j] + bh_r[l * 2048 + j]);
  bp[idx] = v;
}

__global__ void init_state_k(const float* __restrict__ h0_r, const float* __restrict__ h0_i,
                             unsigned short* __restrict__ hring, uint32_t* __restrict__ bar) {
  uint32_t idx = blockIdx.x * 256u + threadIdx.x;   // < 65536 = L*B*H
  if (idx < 64) bar[idx] = 0;                       // zero barrier region (256B)
  int d = idx & 511, b = (idx >> 9) & 63, l = idx >> 15;
  int slot = (l + 1) & 1;                           // layer l first reads slot (l-1)&1
  unsigned short* row = hring + (((size_t)l * 2 + slot) * 64 + b) * 1024;
  row[d]       = f2bf(h0_r[idx]);
  row[512 + d] = f2bf(h0_i[idx]);
}

__global__ void convert_x_k(const float* __restrict__ xr, const float* __restrict__ xi,
                            unsigned short* __restrict__ xbf) {
  uint32_t idx = blockIdx.x * 256u + threadIdx.x;   // < 33,554,432 = T*B*1024
  int k = idx & 1023;
  uint32_t row = idx >> 10;                         // t*64 + b
  float v = (k < 512) ? xr[(size_t)row * 512 + k] : xi[(size_t)row * 512 + (k - 512)];
  xbf[idx] = f2bf(v);
}

// ---------------- main persistent kernel ----------------

__global__ __launch_bounds__(256, 1) void lstm_persist_k(
    const float* __restrict__ xr, const float* __restrict__ xi,
    const float* __restrict__ c0_r, const float* __restrict__ c0_i,
    const unsigned short* __restrict__ wp, const float* __restrict__ bp,
    unsigned short* __restrict__ hring, const unsigned short* __restrict__ xbf,
    float* __restrict__ out, uint32_t* barcnt, uint32_t* bargen, int use_xbf)
{
  __shared__ unsigned short Wlds[32 * KPAD];   // 131,584 B  (cols-major, k contiguous, +8 pad)
  __shared__ float Glds[64 * 33];              //   8,448 B
  __shared__ float bias_s[32];

  const int l   = blockIdx.x >> 7;     // layer
  const int nb  = blockIdx.x & 127;    // n-chunk: cols [32nb, 32nb+32) == hidden d in [4nb, 4nb+4)
  const int tid = threadIdx.x;

  // stage this block's 32x2048 bf16 weight slice into LDS (16B chunks)
  {
    const short8* src = (const short8*)(wp + ((size_t)l * 4096 + (size_t)nb * 32) * 2048);
    for (int i = tid; i < 32 * 256; i += 256) {
      int col = i >> 8, k8 = i & 255;
      *(short8*)(&Wlds[col * KPAD + k8 * 8]) = src[i];
    }
    if (tid < 32) bias_s[tid] = bp[l * 4096 + nb * 32 + tid];
  }

  // elementwise ownership + register-resident cell state
  const int b_e = tid & 63, dd_e = tid >> 6;
  const int d_e = nb * 4 + dd_e;
  float cr = c0_r[(l * 64 + b_e) * 512 + d_e];
  float ci = c0_i[(l * 64 + b_e) * 512 + d_e];
  __syncthreads();

  // MFMA wave assignment: wave w -> n-tile (w&1), m-tiles {2(w>>1), 2(w>>1)+1}
  const int wv = tid >> 6, lane = tid & 63;
  const int nt = wv & 1, mpair = wv >> 1;
  const int quad = lane >> 4, mrow = lane & 15;
  const int b0 = mpair * 32 + mrow;
  const int b1 = b0 + 16;
  const unsigned short* brow = &Wlds[(nt * 16 + mrow) * KPAD];  // B-frag row n = lane&15

  uint32_t mygen = 0;
  long spin_budget = (1L << 24);  // safety: bound any pathological spin, never hit normally

  for (int p = 0; p < NPHASE; ++p) {
    const int t = p - l;
    const bool active = (t >= 0) && (t < 512);
    if (active) {
      const int rs = (p - 1) & 1;   // ring slot written at phase p-1
      const unsigned short* hown = hring + (((size_t)l * 2 + rs) * 64) * 1024;
      const unsigned short* xsrc0 = (l == 1)
          ? (hring + ((size_t)rs * 64) * 1024)            // layer-0 ring == y0[t]
          : (xbf + (size_t)t * 64 * 1024);                // bf16 x cache (if use_xbf)
      const bool cvt_path = (l == 0) && (!use_xbf);
      floatx4 acc0 = {0.f, 0.f, 0.f, 0.f}, acc1 = {0.f, 0.f, 0.f, 0.f};

      for (int kt = 0; kt < 64; ++kt) {
        const int k0 = kt * 32 + quad * 8;
        short8 a0, a1;
        if (kt < 32) {   // k in [0,1024): x-part of u
          if (cvt_path) {
            const float* s0 = ((kt < 16) ? xr : xi) + ((size_t)t * 64) * 512;
            const int kk = k0 & 511;
            const float* q0 = s0 + (size_t)b0 * 512 + kk;
            const float* q1 = s0 + (size_t)b1 * 512 + kk;
            #pragma unroll
            for (int j = 0; j < 8; ++j) { a0[j] = (short)f2bf(q0[j]); a1[j] = (short)f2bf(q1[j]); }
          } else {
            a0 = *(const short8*)(xsrc0 + (size_t)b0 * 1024 + k0);
            a1 = *(const short8*)(xsrc0 + (size_t)b1 * 1024 + k0);
          }
        } else {         // k in [1024,2048): own h
          a0 = *(const short8*)(hown + (size_t)b0 * 1024 + (k0 - 1024));
          a1 = *(const short8*)(hown + (size_t)b1 * 1024 + (k0 - 1024));
        }
        short8 bf = *(const short8*)(brow + k0);
        acc0 = __builtin_amdgcn_mfma_f32_16x16x32_bf16(a0, bf, acc0, 0, 0, 0);
        acc1 = __builtin_amdgcn_mfma_f32_16x16x32_bf16(a1, bf, acc1, 0, 0, 0);
      }
      // store gates (+bias): D lane layout col=lane&15, row=quad*4+reg (m89/m91-verified)
      const int colg = nt * 16 + mrow;
      const float bb = bias_s[colg];
      #pragma unroll
      for (int r = 0; r < 4; ++r) {
        int row0 = mpair * 32 + quad * 4 + r;
        Glds[row0 * 33 + colg]        = acc0[r] + bb;
        Glds[(row0 + 16) * 33 + colg] = acc1[r] + bb;
      }
    }
    __syncthreads();
    if (active) {
      const float* gp = &Glds[b_e * 33 + dd_e * 8];
      float i_r = sigm(gp[0]), f_r = sigm(gp[1]), gc_r = tanhf_(gp[2]), o_r = sigm(gp[3]);
      float i_i = sigm(gp[4]), f_i = sigm(gp[5]), gc_i = tanhf_(gp[6]), o_i = sigm(gp[7]);
      float cr2 = f_r * cr - f_i * ci + i_r * gc_r - i_i * gc_i;
      float ci2 = f_r * ci + f_i * cr + i_r * gc_i + i_i * gc_r;
      cr = cr2; ci = ci2;
      float t_r = tanhf_(cr), t_i = tanhf_(ci);
      float h_r = o_r * t_r - o_i * t_i;
      float h_i = o_r * t_i + o_i * t_r;
      unsigned short* hw = hring + (((size_t)l * 2 + (p & 1)) * 64 + b_e) * 1024;
      hw[d_e]       = f2bf(h_r);
      hw[512 + d_e] = f2bf(h_i);
      if (l == 1) {                       // final-layer sequence output
        size_t o = ((size_t)t * 64 + b_e) * 512 + d_e;
        out[o]            = h_r;
        out[16777216 + o] = h_i;
      }
      if (t == 511) {                     // final hidden states
        size_t o = 33554432u + ((size_t)l * 64 + b_e) * 512 + d_e;
        out[o]         = h_r;
        out[o + 65536] = h_i;
      }
    }
    // ---- grid barrier (all 256 blocks co-resident: 1 block/CU by LDS) ----
    __threadfence();          // agent-scope release of h-ring/out writes
    __syncthreads();
    if (tid == 0) {
      uint32_t old = __hip_atomic_fetch_add(barcnt, 1u, __ATOMIC_ACQ_REL, __HIP_MEMORY_SCOPE_AGENT);
      if (old == 255u) {
        __hip_atomic_store(barcnt, 0u, __ATOMIC_RELAXED, __HIP_MEMORY_SCOPE_AGENT);
        __hip_atomic_store(bargen, mygen + 1u, __ATOMIC_RELEASE, __HIP_MEMORY_SCOPE_AGENT);
      } else {
        while (__hip_atomic_load(bargen, __ATOMIC_ACQUIRE, __HIP_MEMORY_SCOPE_AGENT) == mygen) {
          __builtin_amdgcn_s_sleep(2);
          if (--spin_budget <= 0) break;
        }
      }
    }
    __syncthreads();
    __builtin_amdgcn_fence(__ATOMIC_ACQUIRE, "agent");  // invalidate stale cached h
    mygen++;
  }
}

// ---------------- host ----------------

extern "C" void kernel_launch(void* const* d_in, const int* in_sizes, int n_in,
                              void* d_out, int out_size, void* d_ws, size_t ws_size,
                              hipStream_t stream) {
  const float* seq_r = (const float*)d_in[0];
  const float* seq_i = (const float*)d_in[1];
  const float* h0_r  = (const float*)d_in[2];
  const float* h0_i  = (const float*)d_in[3];
  const float* c0_r  = (const float*)d_in[4];
  const float* c0_i  = (const float*)d_in[5];
  const float* Wi_r  = (const float*)d_in[6];
  const float* Wi_i  = (const float*)d_in[7];
  const float* Wh_r  = (const float*)d_in[8];
  const float* Wh_i  = (const float*)d_in[9];
  const float* bi_r  = (const float*)d_in[10];
  const float* bi_i  = (const float*)d_in[11];
  const float* bh_r  = (const float*)d_in[12];
  const float* bh_i  = (const float*)d_in[13];

  char* ws = (char*)d_ws;
  uint32_t* barcnt = (uint32_t*)ws;
  uint32_t* bargen = (uint32_t*)(ws + 128);
  unsigned short* wp   = (unsigned short*)(ws + OFF_W);
  float*          bias = (float*)(ws + OFF_BIAS);
  unsigned short* hrg  = (unsigned short*)(ws + OFF_H);
  unsigned short* xbf  = (unsigned short*)(ws + OFF_XBF);
  const int use_xbf = (ws_size >= NEED_XBF) ? 1 : 0;

  pack_weights_k<<<65536, 256, 0, stream>>>(Wi_r, Wi_i, Wh_r, Wh_i, wp);
  pack_bias_k<<<32, 256, 0, stream>>>(bi_r, bi_i, bh_r, bh_i, bias);
  init_state_k<<<256, 256, 0, stream>>>(h0_r, h0_i, hrg, barcnt);
  if (use_xbf) convert_x_k<<<131072, 256, 0, stream>>>(seq_r, seq_i, xbf);

  lstm_persist_k<<<256, 256, 0, stream>>>(seq_r, seq_i, c0_r, c0_i, wp, bias,
                                          hrg, xbf, (float*)d_out, barcnt, bargen, use_xbf);
}

// Round 2
// 27029.794 us; speedup vs baseline: 1.5072x; 1.5072x over previous
//
#include <hip/hip_runtime.h>
#include <stdint.h>

// ---------------------------------------------------------------------------
// complexLSTM: T=512, B=64, H=512, L=2   (persistent-kernel, bf16 MFMA)
//   - packed weights per block in MFMA fragment order: block (l,nb) owns
//     gate-cols [32nb,32nb+32); layout [kt][nt][lane][8] bf16 so LDS B-reads
//     are stride-1 ds_read_b128 (0 bank conflicts).
//   - 256 blocks (1/CU via 139.6KB LDS), 4 waves; wave w = m-tile w (batches
//     w*16..w*16+15), computes both 16-col n-tiles -> A loaded once per block.
//   - layer pipelining: layer l active during phases p in [l, l+512)
//   - h exchanged via global 2-slot bf16 ring; c in registers
//   - flag-tree grid barrier: per-block arrival slots (64B stride) + master
//     aggregate + broadcast generation word. NO contended atomic RMW.
// ---------------------------------------------------------------------------

#define NPHASE 513

typedef __attribute__((ext_vector_type(8))) short short8;
typedef __attribute__((ext_vector_type(4))) float floatx4;
typedef float __attribute__((ext_vector_type(4))) floatv4;

#define OFF_W    32768u                     // arr[256] slots (64B stride) + bargen live below
#define SZ_W     (2u*4096u*2048u*2u)        // 33,554,432  packed bf16 weights
#define OFF_BIAS (OFF_W + SZ_W)
#define SZ_BIAS  (2u*4096u*4u)
#define OFF_H    (OFF_BIAS + SZ_BIAS)       // h rings [L][2][64][1024] bf16
#define SZ_H     (2u*2u*64u*1024u*2u)
#define OFF_XBF  (OFF_H + SZ_H)             // optional bf16 x cache
#define SZ_XBF   (512u*64u*1024u*2u)        // 67,108,864
#define NEED_XBF ((size_t)OFF_XBF + SZ_XBF)

__device__ __forceinline__ unsigned short f2bf(float f) {
  union { float f; uint32_t u; } v; v.f = f;
  uint32_t u = v.u;
  uint32_t r = (u + 0x7fffu + ((u >> 16) & 1u)) >> 16;   // RNE
  return (unsigned short)r;
}
__device__ __forceinline__ float sigm(float x)  { return 1.0f / (1.0f + __expf(-x)); }
__device__ __forceinline__ float tanhf_(float x){ return 1.0f - 2.0f / (1.0f + __expf(2.0f * x)); }

// ---------------- prep kernels ----------------

// wp layout: [l][nb][kt(64)][nt(2)][lane(64)][j(8)] bf16 ; lane=(quad<<4)|mrow
//   n_col = nt*16 + mrow (0..31), k = kt*32 + quad*8 + j
__global__ void pack_weights_k(const float* __restrict__ Wi_r, const float* __restrict__ Wi_i,
                               const float* __restrict__ Wh_r, const float* __restrict__ Wh_i,
                               unsigned short* __restrict__ wp) {
  uint32_t idx = blockIdx.x * 256u + threadIdx.x;   // < 16,777,216
  int j    = idx & 7;
  int lane = (idx >> 3) & 63;
  int nt   = (idx >> 9) & 1;
  int kt   = (idx >> 10) & 63;
  int nb   = (idx >> 16) & 127;
  int l    = idx >> 23;
  int mrow = lane & 15, quad = lane >> 4;
  int n_col = nt * 16 + mrow;
  int dd = n_col >> 3, g = n_col & 7;
  int d  = nb * 4 + dd;
  int k  = kt * 32 + quad * 8 + j;
  int jrow = (g & 3) * 512 + d;                 // row in the (4H,H) weight
  int seg = k >> 9, kk = k & 511;
  bool im = (g >= 4);
  const float* src; float sgn = 1.0f;
  if (seg == 0)      { src = im ? Wi_i : Wi_r; }                         // * xr
  else if (seg == 1) { src = im ? Wi_r : Wi_i; if (!im) sgn = -1.0f; }   // * xi
  else if (seg == 2) { src = im ? Wh_i : Wh_r; }                         // * hr
  else               { src = im ? Wh_r : Wh_i; if (!im) sgn = -1.0f; }   // * hi
  float v = sgn * src[((size_t)l * 2048 + jrow) * 512 + kk];
  wp[idx] = f2bf(v);
}

// bias packed as [l][nb][n_col(32)] fp32 (n_col = dd*8+g)
__global__ void pack_bias_k(const float* __restrict__ bi_r, const float* __restrict__ bi_i,
                            const float* __restrict__ bh_r, const float* __restrict__ bh_i,
                            float* __restrict__ bp) {
  uint32_t idx = blockIdx.x * 256u + threadIdx.x;   // < 8192
  int n_col = idx & 31, nb = (idx >> 5) & 127, l = idx >> 12;
  int dd = n_col >> 3, g = n_col & 7;
  int j = (g & 3) * 512 + nb * 4 + dd;
  float v = (g >= 4) ? (bi_i[l * 2048 + j] + bh_i[l * 2048 + j])
                     : (bi_r[l * 2048 + j] + bh_r[l * 2048 + j]);
  bp[idx] = v;
}

__global__ void init_state_k(const float* __restrict__ h0_r, const float* __restrict__ h0_i,
                             unsigned short* __restrict__ hring, uint32_t* __restrict__ bar) {
  uint32_t idx = blockIdx.x * 256u + threadIdx.x;   // < 65536 = L*B*H
  if (idx < 4224) bar[idx] = 0;                     // arr slots + bargen region
  int d = idx & 511, b = (idx >> 9) & 63, l = idx >> 15;
  int slot = (l + 1) & 1;                           // layer l first reads slot (l-1)&1
  unsigned short* row = hring + (((size_t)l * 2 + slot) * 64 + b) * 1024;
  row[d]       = f2bf(h0_r[idx]);
  row[512 + d] = f2bf(h0_i[idx]);
}

__global__ void convert_x_k(const float* __restrict__ xr, const float* __restrict__ xi,
                            unsigned short* __restrict__ xbf) {
  uint32_t idx = blockIdx.x * 256u + threadIdx.x;   // < 33,554,432 = T*B*1024
  int k = idx & 1023;
  uint32_t row = idx >> 10;                         // t*64 + b
  float v = (k < 512) ? xr[(size_t)row * 512 + k] : xi[(size_t)row * 512 + (k - 512)];
  xbf[idx] = f2bf(v);
}

// ---------------- main persistent kernel ----------------

__global__ __launch_bounds__(256, 1) void lstm_persist_k(
    const float* __restrict__ xr, const float* __restrict__ xi,
    const float* __restrict__ c0_r, const float* __restrict__ c0_i,
    const unsigned short* __restrict__ wp, const float* __restrict__ bp,
    unsigned short* __restrict__ hring, const unsigned short* __restrict__ xbf,
    float* __restrict__ out, uint32_t* arr, uint32_t* bargen, int use_xbf)
{
  __shared__ short8 Wb[8192];                  // 131,072 B : [kt][nt][lane] fragments
  __shared__ float Glds[64 * 33];              //   8,448 B
  __shared__ float bias_s[32];

  const int l   = blockIdx.x >> 7;     // layer
  const int nb  = blockIdx.x & 127;    // gate-col chunk [32nb, 32nb+32)
  const int bid = blockIdx.x;
  const int tid = threadIdx.x;

  // stage this block's weight slice into LDS: straight 131,072B contiguous copy
  {
    const short8* src = (const short8*)(wp + (((size_t)l * 128 + nb) << 16));
    #pragma unroll
    for (int i = 0; i < 32; ++i) Wb[i * 256 + tid] = src[i * 256 + tid];
    if (tid < 32) bias_s[tid] = bp[(l * 128 + nb) * 32 + tid];
  }

  // elementwise ownership + register-resident cell state
  const int b_e = tid & 63, dd_e = tid >> 6;
  const int d_e = nb * 4 + dd_e;
  float cr = c0_r[(l * 64 + b_e) * 512 + d_e];
  float ci = c0_i[(l * 64 + b_e) * 512 + d_e];
  __syncthreads();

  // wave w = m-tile w: batches b = w*16 + mrow ; computes both n-tiles
  const int wv = tid >> 6, lane = tid & 63;
  const int quad = lane >> 4, mrow = lane & 15;
  const int bm = wv * 16 + mrow;                  // this lane's A row (batch)
  const size_t arow = (size_t)bm * 1024 + quad * 8;

  for (int p = 0; p < NPHASE; ++p) {
    const int t = p - l;
    const bool active = (t >= 0) && (t < 512);
    if (active) {
      const int rs = (p - 1) & 1;   // ring slot written at phase p-1
      const unsigned short* hown = hring + (((size_t)l * 2 + rs) * 64) * 1024;
      const unsigned short* xsrc = (l == 1)
          ? (hring + ((size_t)rs * 64) * 1024)            // layer-0 ring == y0[t]
          : (xbf + (size_t)t * 64 * 1024);                // bf16 x cache (if use_xbf)
      const bool cvt_path = (l == 0) && (!use_xbf);
      floatx4 acc0 = {0.f, 0.f, 0.f, 0.f}, acc1 = {0.f, 0.f, 0.f, 0.f};

      if (cvt_path) {
        const size_t xtb = ((size_t)t * 64 + bm) * 512 + quad * 8;
        #pragma unroll 8
        for (int kt = 0; kt < 32; ++kt) {
          const float* xb = ((kt < 16) ? xr : xi) + xtb + (kt & 15) * 32;
          floatv4 f0 = *(const floatv4*)xb;
          floatv4 f1 = *(const floatv4*)(xb + 4);
          short8 a;
          #pragma unroll
          for (int jj = 0; jj < 4; ++jj) { a[jj] = (short)f2bf(f0[jj]); a[jj+4] = (short)f2bf(f1[jj]); }
          short8 bf0 = Wb[(kt * 2 + 0) * 64 + lane];
          short8 bf1 = Wb[(kt * 2 + 1) * 64 + lane];
          acc0 = __builtin_amdgcn_mfma_f32_16x16x32_bf16(a, bf0, acc0, 0, 0, 0);
          acc1 = __builtin_amdgcn_mfma_f32_16x16x32_bf16(a, bf1, acc1, 0, 0, 0);
        }
      } else {
        #pragma unroll 8
        for (int kt = 0; kt < 32; ++kt) {
          short8 a = *(const short8*)(xsrc + arow + kt * 32);
          short8 bf0 = Wb[(kt * 2 + 0) * 64 + lane];
          short8 bf1 = Wb[(kt * 2 + 1) * 64 + lane];
          acc0 = __builtin_amdgcn_mfma_f32_16x16x32_bf16(a, bf0, acc0, 0, 0, 0);
          acc1 = __builtin_amdgcn_mfma_f32_16x16x32_bf16(a, bf1, acc1, 0, 0, 0);
        }
      }
      #pragma unroll 8
      for (int kt = 32; kt < 64; ++kt) {
        short8 a = *(const short8*)(hown + arow + (kt - 32) * 32);
        short8 bf0 = Wb[(kt * 2 + 0) * 64 + lane];
        short8 bf1 = Wb[(kt * 2 + 1) * 64 + lane];
        acc0 = __builtin_amdgcn_mfma_f32_16x16x32_bf16(a, bf0, acc0, 0, 0, 0);
        acc1 = __builtin_amdgcn_mfma_f32_16x16x32_bf16(a, bf1, acc1, 0, 0, 0);
      }
      // D layout: col = lane&15, row(within m-tile) = quad*4 + r  (m89/m91)
      const float bb0 = bias_s[mrow], bb1 = bias_s[16 + mrow];
      const int rowb = wv * 16 + quad * 4;
      #pragma unroll
      for (int r = 0; r < 4; ++r) {
        Glds[(rowb + r) * 33 + mrow]      = acc0[r] + bb0;
        Glds[(rowb + r) * 33 + 16 + mrow] = acc1[r] + bb1;
      }
    }
    __syncthreads();
    if (active) {
      const float* gp = &Glds[b_e * 33 + dd_e * 8];
      float i_r = sigm(gp[0]), f_r = sigm(gp[1]), gc_r = tanhf_(gp[2]), o_r = sigm(gp[3]);
      float i_i = sigm(gp[4]), f_i = sigm(gp[5]), gc_i = tanhf_(gp[6]), o_i = sigm(gp[7]);
      float cr2 = f_r * cr - f_i * ci + i_r * gc_r - i_i * gc_i;
      float ci2 = f_r * ci + f_i * cr + i_r * gc_i + i_i * gc_r;
      cr = cr2; ci = ci2;
      float t_r = tanhf_(cr), t_i = tanhf_(ci);
      float h_r = o_r * t_r - o_i * t_i;
      float h_i = o_r * t_i + o_i * t_r;
      unsigned short* hw = hring + (((size_t)l * 2 + (p & 1)) * 64 + b_e) * 1024;
      hw[d_e]       = f2bf(h_r);
      hw[512 + d_e] = f2bf(h_i);
      if (l == 1) {                       // final-layer sequence output
        size_t o = ((size_t)t * 64 + b_e) * 512 + d_e;
        out[o]            = h_r;
        out[16777216 + o] = h_i;
      }
      if (t == 511) {                     // final hidden states
        size_t o = 33554432u + ((size_t)l * 64 + b_e) * 512 + d_e;
        out[o]         = h_r;
        out[o + 65536] = h_i;
      }
    }
    // ---- flag-tree grid barrier (all 256 blocks co-resident: 1/CU by LDS) ----
    __threadfence();                      // release h-ring/out writes (agent scope)
    __syncthreads();
    const uint32_t g = (uint32_t)p + 1u;
    long budget = (1L << 22);
    if (bid == 0) {
      // master: thread t polls block t's arrival slot (64B stride, no RMW)
      if (tid > 0) {
        while (__hip_atomic_load(&arr[tid * 16], __ATOMIC_RELAXED, __HIP_MEMORY_SCOPE_AGENT) < g) {
          __builtin_amdgcn_s_sleep(1);
          if (--budget <= 0) break;
        }
      }
      __syncthreads();
      if (tid == 0) {
        __builtin_amdgcn_fence(__ATOMIC_ACQUIRE, "agent");   // pair w/ arrival releases
        __hip_atomic_store(bargen, g, __ATOMIC_RELEASE, __HIP_MEMORY_SCOPE_AGENT);
      }
    } else {
      if (tid == 0) {
        __hip_atomic_store(&arr[bid * 16], g, __ATOMIC_RELEASE, __HIP_MEMORY_SCOPE_AGENT);
        while (__hip_atomic_load(bargen, __ATOMIC_RELAXED, __HIP_MEMORY_SCOPE_AGENT) < g) {
          __builtin_amdgcn_s_sleep(1);
          if (--budget <= 0) break;
        }
      }
    }
    __syncthreads();
    __builtin_amdgcn_fence(__ATOMIC_ACQUIRE, "agent");  // invalidate stale cached h
  }
}

// ---------------- host ----------------

extern "C" void kernel_launch(void* const* d_in, const int* in_sizes, int n_in,
                              void* d_out, int out_size, void* d_ws, size_t ws_size,
                              hipStream_t stream) {
  const float* seq_r = (const float*)d_in[0];
  const float* seq_i = (const float*)d_in[1];
  const float* h0_r  = (const float*)d_in[2];
  const float* h0_i  = (const float*)d_in[3];
  const float* c0_r  = (const float*)d_in[4];
  const float* c0_i  = (const float*)d_in[5];
  const float* Wi_r  = (const float*)d_in[6];
  const float* Wi_i  = (const float*)d_in[7];
  const float* Wh_r  = (const float*)d_in[8];
  const float* Wh_i  = (const float*)d_in[9];
  const float* bi_r  = (const float*)d_in[10];
  const float* bi_i  = (const float*)d_in[11];
  const float* bh_r  = (const float*)d_in[12];
  const float* bh_i  = (const float*)d_in[13];

  char* ws = (char*)d_ws;
  uint32_t* arr    = (uint32_t*)ws;                 // 256 slots, 64B stride
  uint32_t* bargen = (uint32_t*)(ws + 16384);
  unsigned short* wp   = (unsigned short*)(ws + OFF_W);
  float*          bias = (float*)(ws + OFF_BIAS);
  unsigned short* hrg  = (unsigned short*)(ws + OFF_H);
  unsigned short* xbf  = (unsigned short*)(ws + OFF_XBF);
  const int use_xbf = (ws_size >= NEED_XBF) ? 1 : 0;

  pack_weights_k<<<65536, 256, 0, stream>>>(Wi_r, Wi_i, Wh_r, Wh_i, wp);
  pack_bias_k<<<32, 256, 0, stream>>>(bi_r, bi_i, bh_r, bh_i, bias);
  init_state_k<<<256, 256, 0, stream>>>(h0_r, h0_i, hrg, arr);
  if (use_xbf) convert_x_k<<<131072, 256, 0, stream>>>(seq_r, seq_i, xbf);

  lstm_persist_k<<<256, 256, 0, stream>>>(seq_r, seq_i, c0_r, c0_i, wp, bias,
                                          hrg, xbf, (float*)d_out, arr, bargen, use_xbf);
}

// Round 3
// 11515.417 us; speedup vs baseline: 3.5379x; 2.3473x over previous
//
#include <hip/hip_runtime.h>
#include <stdint.h>

// ---------------------------------------------------------------------------
// complexLSTM: T=512, B=64, H=512, L=2   (persistent-kernel, bf16 MFMA)
//   Round 3: fence-free write-through sync protocol.
//   - h-state: u32-packed (hi<<16|hr) per (b,d); WRITTEN via relaxed
//     agent-scope atomic stores (write-through, no dirty L2, no wbl2 needed);
//     READ via plain cached dwordx4 after a per-phase acquire-inv.
//   - out: relaxed agent-scope atomic u32 stores (write-through; L2 stays clean)
//   - barrier: per-block private lines. Master polls 256 distinct arrival
//     lines; broadcasts gen to 256 distinct lines; each block polls own line.
//     No atomic RMW, no same-line multi-CU fan-in, no release fences
//     (__syncthreads' vmcnt(0) ack of write-through stores IS the release).
//   - weights packed per block in MFMA fragment order (k-order matches the
//     interleaved h layout; layer-0 x-segment stays planar bf16).
// ---------------------------------------------------------------------------

#define NPHASE 513

typedef __attribute__((ext_vector_type(8))) short short8;
typedef __attribute__((ext_vector_type(4))) float floatx4;
typedef float __attribute__((ext_vector_type(4))) floatv4;

#define OFF_W    32768u                     // below: arr[256] + gen_bc[256] lines
#define SZ_W     (2u*4096u*2048u*2u)        // 33,554,432  packed bf16 weights
#define OFF_BIAS (OFF_W + SZ_W)
#define SZ_BIAS  (2u*4096u*4u)
#define OFF_H    (OFF_BIAS + SZ_BIAS)       // h rings [L][2][64][512] u32 (hi|hr)
#define SZ_H     (2u*2u*64u*512u*4u)
#define OFF_XBF  (OFF_H + SZ_H)             // optional bf16 x cache (planar)
#define SZ_XBF   (512u*64u*1024u*2u)        // 67,108,864
#define NEED_XBF ((size_t)OFF_XBF + SZ_XBF)

__device__ __forceinline__ unsigned short f2bf(float f) {
  union { float f; uint32_t u; } v; v.f = f;
  uint32_t u = v.u;
  uint32_t r = (u + 0x7fffu + ((u >> 16) & 1u)) >> 16;   // RNE
  return (unsigned short)r;
}
__device__ __forceinline__ float sigm(float x)  { return 1.0f / (1.0f + __expf(-x)); }
__device__ __forceinline__ float tanhf_(float x){ return 1.0f - 2.0f / (1.0f + __expf(2.0f * x)); }

// ---------------- prep kernels ----------------

// wp layout: [l][nb][kt(64)][nt(2)][lane(64)][j(8)] bf16 ; lane=(quad<<4)|mrow
// k-order (per layer):
//   l==0: k<1024 planar  [xr(512)|xi(512)] (matches xbf / fp32 cvt path)
//   l==1: k<1024 interleaved (d=k>>1, ri=k&1) — layer-0 h-ring IS the input
//   both: k>=1024 interleaved h (d=(k-1024)>>1, ri)
__global__ void pack_weights_k(const float* __restrict__ Wi_r, const float* __restrict__ Wi_i,
                               const float* __restrict__ Wh_r, const float* __restrict__ Wh_i,
                               unsigned short* __restrict__ wp) {
  uint32_t idx = blockIdx.x * 256u + threadIdx.x;   // < 16,777,216
  int j    = idx & 7;
  int lane = (idx >> 3) & 63;
  int nt   = (idx >> 9) & 1;
  int kt   = (idx >> 10) & 63;
  int nb   = (idx >> 16) & 127;
  int l    = idx >> 23;
  int mrow = lane & 15, quad = lane >> 4;
  int n_col = nt * 16 + mrow;
  int dd = n_col >> 3, g = n_col & 7;
  int jrow = (g & 3) * 512 + nb * 4 + dd;       // row in the (4H,H) weight
  int k = kt * 32 + quad * 8 + j;
  bool im = (g >= 4);
  size_t ro = ((size_t)l * 2048 + jrow) * 512;
  float v;
  if (k < 1024 && l == 0) {                      // planar x segment
    int seg = k >> 9, kk = k & 511;
    if (seg == 0) v = im ? Wi_i[ro + kk] :  Wi_r[ro + kk];
    else          v = im ? Wi_r[ro + kk] : -Wi_i[ro + kk];
  } else {                                       // interleaved segment
    int kk = k & 1023;
    int d = kk >> 1, ri = kk & 1;
    const float* Wr = (k < 1024) ? Wi_r : Wh_r;
    const float* Wm = (k < 1024) ? Wi_i : Wh_i;
    if (ri == 0) v = im ? Wm[ro + d] :  Wr[ro + d];
    else         v = im ? Wr[ro + d] : -Wm[ro + d];
  }
  wp[idx] = f2bf(v);
}

// bias packed as [l][nb][n_col(32)] fp32 (n_col = dd*8+g)
__global__ void pack_bias_k(const float* __restrict__ bi_r, const float* __restrict__ bi_i,
                            const float* __restrict__ bh_r, const float* __restrict__ bh_i,
                            float* __restrict__ bp) {
  uint32_t idx = blockIdx.x * 256u + threadIdx.x;   // < 8192
  int n_col = idx & 31, nb = (idx >> 5) & 127, l = idx >> 12;
  int dd = n_col >> 3, g = n_col & 7;
  int j = (g & 3) * 512 + nb * 4 + dd;
  float v = (g >= 4) ? (bi_i[l * 2048 + j] + bh_i[l * 2048 + j])
                     : (bi_r[l * 2048 + j] + bh_r[l * 2048 + j]);
  bp[idx] = v;
}

__global__ void init_state_k(const float* __restrict__ h0_r, const float* __restrict__ h0_i,
                             uint32_t* __restrict__ hring32, uint32_t* __restrict__ bar) {
  uint32_t idx = blockIdx.x * 256u + threadIdx.x;   // < 65536 = L*B*H
  if (idx < 8192) bar[idx] = 0;                     // arr + gen_bc lines (32KB)
  int d = idx & 511, b = (idx >> 9) & 63, l = idx >> 15;
  int slot = (l + 1) & 1;                           // layer l first reads slot (l-1)&1
  uint32_t* row = hring32 + (((size_t)l * 2 + slot) * 64 + b) * 512;
  row[d] = ((uint32_t)f2bf(h0_i[idx]) << 16) | (uint32_t)f2bf(h0_r[idx]);
}

__global__ void convert_x_k(const float* __restrict__ xr, const float* __restrict__ xi,
                            unsigned short* __restrict__ xbf) {
  uint32_t idx = blockIdx.x * 256u + threadIdx.x;   // < 33,554,432 = T*B*1024
  int k = idx & 1023;
  uint32_t row = idx >> 10;                         // t*64 + b
  float v = (k < 512) ? xr[(size_t)row * 512 + k] : xi[(size_t)row * 512 + (k - 512)];
  xbf[idx] = f2bf(v);
}

// ---------------- main persistent kernel ----------------

__global__ __launch_bounds__(256, 1) void lstm_persist_k(
    const float* __restrict__ xr, const float* __restrict__ xi,
    const float* __restrict__ c0_r, const float* __restrict__ c0_i,
    const unsigned short* __restrict__ wp, const float* __restrict__ bp,
    uint32_t* __restrict__ hring32, const unsigned short* __restrict__ xbf,
    float* __restrict__ out, uint32_t* arr, uint32_t* gen_bc, int use_xbf)
{
  __shared__ short8 Wb[8192];                  // 131,072 B : [kt][nt][lane] fragments
  __shared__ float Glds[64 * 33];              //   8,448 B
  __shared__ float bias_s[32];

  const int l   = blockIdx.x >> 7;     // layer
  const int nb  = blockIdx.x & 127;    // gate-col chunk [32nb, 32nb+32)
  const int bid = blockIdx.x;
  const int tid = threadIdx.x;

  // stage this block's weight slice into LDS: straight 131,072B contiguous copy
  {
    const short8* src = (const short8*)(wp + (((size_t)l * 128 + nb) << 16));
    #pragma unroll
    for (int i = 0; i < 32; ++i) Wb[i * 256 + tid] = src[i * 256 + tid];
    if (tid < 32) bias_s[tid] = bp[(l * 128 + nb) * 32 + tid];
  }

  // elementwise ownership + register-resident cell state
  const int b_e = tid & 63, dd_e = tid >> 6;
  const int d_e = nb * 4 + dd_e;
  float cr = c0_r[(l * 64 + b_e) * 512 + d_e];
  float ci = c0_i[(l * 64 + b_e) * 512 + d_e];
  __syncthreads();

  // wave w = m-tile w: batches b = w*16 + mrow ; computes both n-tiles
  const int wv = tid >> 6, lane = tid & 63;
  const int quad = lane >> 4, mrow = lane & 15;
  const int bm = wv * 16 + mrow;                  // this lane's A row (batch)

  for (int p = 0; p < NPHASE; ++p) {
    const int t = p - l;
    const bool active = (t >= 0) && (t < 512);
    if (active) {
      const int rs = (p - 1) & 1;   // ring slot written at phase p-1
      // interleaved u32 h rows: hring32[(l*2+rs)*64 + b][512]
      const uint32_t* hown = hring32 + (((size_t)l * 2 + rs) * 64 + bm) * 512;
      const uint32_t* xs32 = hring32 + (((size_t)rs) * 64 + bm) * 512;   // layer-0 ring
      const bool cvt_path = (l == 0) && (!use_xbf);
      floatx4 acc0 = {0.f, 0.f, 0.f, 0.f}, acc1 = {0.f, 0.f, 0.f, 0.f};

      if (l == 0) {
        if (cvt_path) {
          const size_t xtb = ((size_t)t * 64 + bm) * 512 + quad * 8;
          #pragma unroll 8
          for (int kt = 0; kt < 32; ++kt) {
            const float* xb = ((kt < 16) ? xr : xi) + xtb + (kt & 15) * 32;
            floatv4 f0 = *(const floatv4*)xb;
            floatv4 f1 = *(const floatv4*)(xb + 4);
            short8 a;
            #pragma unroll
            for (int jj = 0; jj < 4; ++jj) { a[jj] = (short)f2bf(f0[jj]); a[jj+4] = (short)f2bf(f1[jj]); }
            short8 bf0 = Wb[(kt * 2 + 0) * 64 + lane];
            short8 bf1 = Wb[(kt * 2 + 1) * 64 + lane];
            acc0 = __builtin_amdgcn_mfma_f32_16x16x32_bf16(a, bf0, acc0, 0, 0, 0);
            acc1 = __builtin_amdgcn_mfma_f32_16x16x32_bf16(a, bf1, acc1, 0, 0, 0);
          }
        } else {
          const unsigned short* xb = xbf + ((size_t)t * 64 + bm) * 1024 + quad * 8;
          #pragma unroll 8
          for (int kt = 0; kt < 32; ++kt) {
            short8 a = *(const short8*)(xb + kt * 32);
            short8 bf0 = Wb[(kt * 2 + 0) * 64 + lane];
            short8 bf1 = Wb[(kt * 2 + 1) * 64 + lane];
            acc0 = __builtin_amdgcn_mfma_f32_16x16x32_bf16(a, bf0, acc0, 0, 0, 0);
            acc1 = __builtin_amdgcn_mfma_f32_16x16x32_bf16(a, bf1, acc1, 0, 0, 0);
          }
        }
      } else {
        const uint32_t* xb = xs32 + quad * 4;
        #pragma unroll 8
        for (int kt = 0; kt < 32; ++kt) {
          short8 a = *(const short8*)(xb + kt * 16);
          short8 bf0 = Wb[(kt * 2 + 0) * 64 + lane];
          short8 bf1 = Wb[(kt * 2 + 1) * 64 + lane];
          acc0 = __builtin_amdgcn_mfma_f32_16x16x32_bf16(a, bf0, acc0, 0, 0, 0);
          acc1 = __builtin_amdgcn_mfma_f32_16x16x32_bf16(a, bf1, acc1, 0, 0, 0);
        }
      }
      {
        const uint32_t* hb = hown + quad * 4;
        #pragma unroll 8
        for (int kt = 32; kt < 64; ++kt) {
          short8 a = *(const short8*)(hb + (kt - 32) * 16);
          short8 bf0 = Wb[(kt * 2 + 0) * 64 + lane];
          short8 bf1 = Wb[(kt * 2 + 1) * 64 + lane];
          acc0 = __builtin_amdgcn_mfma_f32_16x16x32_bf16(a, bf0, acc0, 0, 0, 0);
          acc1 = __builtin_amdgcn_mfma_f32_16x16x32_bf16(a, bf1, acc1, 0, 0, 0);
        }
      }
      // D layout: col = lane&15, row(within m-tile) = quad*4 + r  (m89/m91)
      const float bb0 = bias_s[mrow], bb1 = bias_s[16 + mrow];
      const int rowb = wv * 16 + quad * 4;
      #pragma unroll
      for (int r = 0; r < 4; ++r) {
        Glds[(rowb + r) * 33 + mrow]      = acc0[r] + bb0;
        Glds[(rowb + r) * 33 + 16 + mrow] = acc1[r] + bb1;
      }
    }
    __syncthreads();
    if (active) {
      const float* gp = &Glds[b_e * 33 + dd_e * 8];
      float i_r = sigm(gp[0]), f_r = sigm(gp[1]), gc_r = tanhf_(gp[2]), o_r = sigm(gp[3]);
      float i_i = sigm(gp[4]), f_i = sigm(gp[5]), gc_i = tanhf_(gp[6]), o_i = sigm(gp[7]);
      float cr2 = f_r * cr - f_i * ci + i_r * gc_r - i_i * gc_i;
      float ci2 = f_r * ci + f_i * cr + i_r * gc_i + i_i * gc_r;
      cr = cr2; ci = ci2;
      float t_r = tanhf_(cr), t_i = tanhf_(ci);
      float h_r = o_r * t_r - o_i * t_i;
      float h_i = o_r * t_i + o_i * t_r;
      // write-through packed h (relaxed agent atomic: no dirty L2, acked at MALL)
      uint32_t hp = ((uint32_t)f2bf(h_i) << 16) | (uint32_t)f2bf(h_r);
      uint32_t* hw = hring32 + (((size_t)l * 2 + (p & 1)) * 64 + b_e) * 512;
      __hip_atomic_store(&hw[d_e], hp, __ATOMIC_RELAXED, __HIP_MEMORY_SCOPE_AGENT);
      if (l == 1) {                       // final-layer sequence output (write-through)
        size_t o = ((size_t)t * 64 + b_e) * 512 + d_e;
        __hip_atomic_store((uint32_t*)(out + o), __float_as_uint(h_r),
                           __ATOMIC_RELAXED, __HIP_MEMORY_SCOPE_AGENT);
        __hip_atomic_store((uint32_t*)(out + 16777216 + o), __float_as_uint(h_i),
                           __ATOMIC_RELAXED, __HIP_MEMORY_SCOPE_AGENT);
      }
      if (t == 511) {                     // final hidden states
        size_t o = 33554432u + ((size_t)l * 64 + b_e) * 512 + d_e;
        __hip_atomic_store((uint32_t*)(out + o), __float_as_uint(h_r),
                           __ATOMIC_RELAXED, __HIP_MEMORY_SCOPE_AGENT);
        __hip_atomic_store((uint32_t*)(out + o + 65536), __float_as_uint(h_i),
                           __ATOMIC_RELAXED, __HIP_MEMORY_SCOPE_AGENT);
      }
    }
    // ---- fence-free flag barrier ----
    // __syncthreads emits s_waitcnt vmcnt(0): all write-through stores are
    // acked at the coherence point before any arrival store issues. That IS
    // the release; no buffer_wbl2 anywhere.
    __syncthreads();
    const uint32_t g = (uint32_t)p + 1u;
    long budget = (1L << 22);
    if (bid == 0) {
      if (tid > 0) {      // thread i polls block i's private arrival line
        while (__hip_atomic_load(&arr[tid * 16], __ATOMIC_RELAXED, __HIP_MEMORY_SCOPE_AGENT) < g) {
          if (--budget <= 0) break;
        }
      }
      __syncthreads();    // all arrivals observed
      __hip_atomic_store(&gen_bc[tid * 16], g, __ATOMIC_RELAXED, __HIP_MEMORY_SCOPE_AGENT);
    } else {
      if (tid == 0)
        __hip_atomic_store(&arr[bid * 16], g, __ATOMIC_RELAXED, __HIP_MEMORY_SCOPE_AGENT);
      // all 4 waves poll the block's PRIVATE broadcast line (1 line, 4 readers)
      while (__hip_atomic_load(&gen_bc[bid * 16], __ATOMIC_RELAXED, __HIP_MEMORY_SCOPE_AGENT) < g) {
        if (--budget <= 0) break;
      }
    }
    // acquire: invalidate L1/L2 so next phase's cached h reads see MALL data
    __builtin_amdgcn_fence(__ATOMIC_ACQUIRE, "agent");
  }
}

// ---------------- host ----------------

extern "C" void kernel_launch(void* const* d_in, const int* in_sizes, int n_in,
                              void* d_out, int out_size, void* d_ws, size_t ws_size,
                              hipStream_t stream) {
  const float* seq_r = (const float*)d_in[0];
  const float* seq_i = (const float*)d_in[1];
  const float* h0_r  = (const float*)d_in[2];
  const float* h0_i  = (const float*)d_in[3];
  const float* c0_r  = (const float*)d_in[4];
  const float* c0_i  = (const float*)d_in[5];
  const float* Wi_r  = (const float*)d_in[6];
  const float* Wi_i  = (const float*)d_in[7];
  const float* Wh_r  = (const float*)d_in[8];
  const float* Wh_i  = (const float*)d_in[9];
  const float* bi_r  = (const float*)d_in[10];
  const float* bi_i  = (const float*)d_in[11];
  const float* bh_r  = (const float*)d_in[12];
  const float* bh_i  = (const float*)d_in[13];

  char* ws = (char*)d_ws;
  uint32_t* arr    = (uint32_t*)ws;                 // 256 lines, 64B stride
  uint32_t* gen_bc = (uint32_t*)(ws + 16384);       // 256 lines, 64B stride
  unsigned short* wp   = (unsigned short*)(ws + OFF_W);
  float*          bias = (float*)(ws + OFF_BIAS);
  uint32_t*       hrg  = (uint32_t*)(ws + OFF_H);
  unsigned short* xbf  = (unsigned short*)(ws + OFF_XBF);
  const int use_xbf = (ws_size >= NEED_XBF) ? 1 : 0;

  pack_weights_k<<<65536, 256, 0, stream>>>(Wi_r, Wi_i, Wh_r, Wh_i, wp);
  pack_bias_k<<<32, 256, 0, stream>>>(bi_r, bi_i, bh_r, bh_i, bias);
  init_state_k<<<256, 256, 0, stream>>>(h0_r, h0_i, hrg, arr);
  if (use_xbf) convert_x_k<<<131072, 256, 0, stream>>>(seq_r, seq_i, xbf);

  lstm_persist_k<<<256, 256, 0, stream>>>(seq_r, seq_i, c0_r, c0_i, wp, bias,
                                          hrg, xbf, (float*)d_out, arr, gen_bc, use_xbf);
}